// Round 8
// baseline (1130.570 us; speedup 1.0000x reference)
//
#include <hip/hip_runtime.h>
#include <hip/hip_bf16.h>
#include <hip/hip_cooperative_groups.h>

namespace cg = cooperative_groups;

typedef __attribute__((ext_vector_type(8))) short short8;
typedef __attribute__((ext_vector_type(4))) float f32x4;

#define INF_F 3.4e38f

__device__ __forceinline__ void gload16(const void* g, void* l) {
    __builtin_amdgcn_global_load_lds((const __attribute__((address_space(1))) unsigned*)g,
                                     (__attribute__((address_space(3))) unsigned*)l, 16, 0, 0);
}

// ---------------- fp32 -> bf16 + row norms (512 cols) for BOTH fv and mb, + init ----------------
__global__ void k_conv(const float* __restrict__ fv, const float* __restrict__ mbp,
                       unsigned short* __restrict__ fvb, unsigned short* __restrict__ mbb,
                       float* __restrict__ fnorm, float* __restrict__ mnorm,
                       float* ps_sq, int* ncand, float* cand_val) {
    int t = threadIdx.x, wid = t >> 6, lane = t & 63;
    if (blockIdx.x == 0) {
        if (t == 0) ncand[0] = 0;
        if (t < 64) ((unsigned*)cand_val)[t] = 0x7f800000u;
    }
    int row = blockIdx.x * 4 + wid;
    const float* in; unsigned short* outb; float* norm; int r;
    if (row < 8192) {
        in = fv; outb = fvb; norm = fnorm; r = row;
        if (lane == 0) ((unsigned*)ps_sq)[row] = 0x7f800000u;   // +inf init
    } else if (row < 33192) {
        in = mbp; outb = mbb; norm = mnorm; r = row - 8192;
    } else return;
    const float4* p = (const float4*)(in + (size_t)r * 512) + lane * 2;
    float4 a = p[0], b = p[1];
    float n = a.x*a.x + a.y*a.y + a.z*a.z + a.w*a.w
            + b.x*b.x + b.y*b.y + b.z*b.z + b.w*b.w;
    float vals[8] = {a.x, a.y, a.z, a.w, b.x, b.y, b.z, b.w};
    unsigned short h[8];
    #pragma unroll
    for (int e = 0; e < 8; ++e) {
        unsigned u = __float_as_uint(vals[e]);
        h[e] = (unsigned short)((u + 0x7fffu + ((u >> 16) & 1u)) >> 16);  // RNE
    }
    *(uint4*)(outb + (size_t)r * 512 + lane * 8) = *(uint4*)h;
    #pragma unroll
    for (int s = 1; s < 64; s <<= 1) n += __shfl_xor(n, s, 64);
    if (lane == 0) norm[r] = n;
}

// ---------------- fused GEMM + per-row min (R5/R7-proven m97 structure) ----------------
__global__ __launch_bounds__(256, 2)
void k_gemm_min(const unsigned short* __restrict__ A, const unsigned short* __restrict__ B,
                const float* __restrict__ fnorm, const float* __restrict__ mnorm,
                float* __restrict__ ps_sq) {
    __shared__ unsigned short At[128 * 64];
    __shared__ unsigned short Bt[128 * 64];
    int tid = threadIdx.x, wid = tid >> 6, lane = tid & 63;
    int bid = blockIdx.x;
    int pos = bid >> 3;
    int rb = ((bid & 7) << 3) | (pos & 7);   // 0..63
    int cb = pos >> 3;                        // 0..195
    int brow = rb * 128, bcol = cb * 128;
    int wm = (wid >> 1) * 64, wn = (wid & 1) * 64;

    f32x4 acc[4][4] = {};
    int lr = lane >> 3;
    int lkswz = ((lane & 7) ^ lr) * 8;        // pre-swizzled source column (elems)

    for (int k0 = 0; k0 < 512; k0 += 64) {
        #pragma unroll
        for (int c = 0; c < 4; ++c) {
            int ch = wid + c * 4;
            int row = ch * 8 + lr;
            gload16(A + (size_t)(brow + row) * 512 + k0 + lkswz, &At[ch * 512]);
            int srow = bcol + row; if (srow > 24999) srow = 24999;
            gload16(B + (size_t)srow * 512 + k0 + lkswz, &Bt[ch * 512]);
        }
        __syncthreads();
        #pragma unroll
        for (int kk = 0; kk < 2; ++kk) {
            short8 af[4], bf[4];
            int ko = kk * 32 + (lane >> 4) * 8;
            #pragma unroll
            for (int mi = 0; mi < 4; ++mi) {
                int r = wm + mi * 16 + (lane & 15);
                af[mi] = *(const short8*)&At[r * 64 + (ko ^ ((r & 7) << 3))];
            }
            #pragma unroll
            for (int ni = 0; ni < 4; ++ni) {
                int r = wn + ni * 16 + (lane & 15);
                bf[ni] = *(const short8*)&Bt[r * 64 + (ko ^ ((r & 7) << 3))];
            }
            #pragma unroll
            for (int mi = 0; mi < 4; ++mi)
                #pragma unroll
                for (int ni = 0; ni < 4; ++ni)
                    acc[mi][ni] = __builtin_amdgcn_mfma_f32_16x16x32_bf16(af[mi], bf[ni], acc[mi][ni], 0, 0, 0);
        }
        __syncthreads();
    }

    float mnv[4];
    #pragma unroll
    for (int ni = 0; ni < 4; ++ni) {
        int col = bcol + wn + ni * 16 + (lane & 15);
        mnv[ni] = (col < 25000) ? mnorm[col] : INF_F;
    }
    #pragma unroll
    for (int mi = 0; mi < 4; ++mi) {
        #pragma unroll
        for (int r = 0; r < 4; ++r) {
            float v = INF_F;
            #pragma unroll
            for (int ni = 0; ni < 4; ++ni) v = fminf(v, mnv[ni] - 2.0f * acc[mi][ni][r]);
            #pragma unroll
            for (int s = 1; s < 16; s <<= 1) v = fminf(v, __shfl_xor(v, s, 64));
            if ((lane & 15) == 0) {
                int row = brow + wm + mi * 16 + (lane >> 4) * 4 + r;
                float sq = v + fnorm[row];
                atomicMin((unsigned*)&ps_sq[row], __float_as_uint(sq));
            }
        }
    }
}

// ---------------- fused tail: cand -> score -> argmax+dists -> top-b+softmax ----------------
// mode < 0: cooperative single launch with grid.sync between phases.
// mode 0..3: run only that phase (fallback as 4 plain launches). No early returns.
__global__ __launch_bounds__(256, 4)
void k_tail(const float* __restrict__ fv, const float* __restrict__ mb,
            const float* __restrict__ ps_sq, float* __restrict__ out0,
            int* ncand, int* cand_pix, int* cand_bat, float* cand_val,
            float* __restrict__ exact_d, const int* __restrict__ bp,
            float* __restrict__ out_img, int mode) {
    cg::grid_group grid = cg::this_grid();
    __shared__ float s_smax[4]; __shared__ int s_scnt;
    __shared__ float s_wbv[4]; __shared__ int s_wbi[4];
    __shared__ float s_seld[128];
    __shared__ float s_gbv; __shared__ int s_gbi;

    int t = threadIdx.x, wid = t >> 6, lane = t & 63;

    // ---------- P0: out0 + per-batch candidate gather (blocks 0..7) ----------
    if (mode < 0 || mode == 0) {
        if (blockIdx.x < 8) {
            int b = blockIdx.x;
            const float* base = ps_sq + b * 1024;
            float v[4]; float m = -INF_F;
            #pragma unroll
            for (int i = 0; i < 4; ++i) {
                v[i] = base[t + i * 256];
                out0[b * 1024 + t + i * 256] = sqrtf(fmaxf(v[i], 0.0f));
                m = fmaxf(m, v[i]);
            }
            #pragma unroll
            for (int s = 1; s < 64; s <<= 1) m = fmaxf(m, __shfl_xor(m, s, 64));
            if (lane == 0) s_smax[wid] = m;
            if (t == 0) s_scnt = 0;
            __syncthreads();
            float bm = fmaxf(fmaxf(s_smax[0], s_smax[1]), fmaxf(s_smax[2], s_smax[3]));
            #pragma unroll
            for (int i = 0; i < 4; ++i) {
                if (v[i] >= bm - 8.0f) {           // margin >> 2x worst-case bf16 dot error
                    int s = atomicAdd(&s_scnt, 1);
                    if (s < 8) {
                        int g = atomicAdd(ncand, 1);
                        if (g < 64) { cand_pix[g] = b * 1024 + t + i * 256; cand_bat[g] = b; }
                    }
                }
            }
        }
    }
    if (mode < 0) { __threadfence(); grid.sync(); }

    // ---------- P1: exact fp32 min-dist per candidate (4 cands/item, items strided) ----------
    if (mode < 0 || mode == 1) {
        int nct = ncand[0]; if (nct > 64) nct = 64;
        int nitems = ((nct + 3) >> 2) * 391;
        for (int item = blockIdx.x; item < nitems; item += gridDim.x) {
            int c0 = (item / 391) * 4;
            int chunk = item % 391;
            int p0i = cand_pix[c0];
            int p1i = cand_pix[c0 + 1 < nct ? c0 + 1 : c0];
            int p2i = cand_pix[c0 + 2 < nct ? c0 + 2 : c0];
            int p3i = cand_pix[c0 + 3 < nct ? c0 + 3 : c0];
            const float4* s0 = (const float4*)(fv + (size_t)p0i * 512) + lane * 2;
            const float4* s1 = (const float4*)(fv + (size_t)p1i * 512) + lane * 2;
            const float4* s2 = (const float4*)(fv + (size_t)p2i * 512) + lane * 2;
            const float4* s3 = (const float4*)(fv + (size_t)p3i * 512) + lane * 2;
            float4 ca0 = s0[0], ca1 = s0[1];
            float4 cb0 = s1[0], cb1 = s1[1];
            float4 cc0 = s2[0], cc1 = s2[1];
            float4 cd0 = s3[0], cd1 = s3[1];
            float m0v = INF_F, m1v = INF_F, m2v = INF_F, m3v = INF_F;
            int rbase = chunk * 64 + wid * 16;
            for (int i = 0; i < 16; ++i) {
                int r = rbase + i;
                if (r >= 25000) break;
                const float4* mp = (const float4*)(mb + (size_t)r * 512) + lane * 2;
                float4 x0 = mp[0], x1 = mp[1];
                float d, p0 = 0.f, p1 = 0.f, p2 = 0.f, p3 = 0.f;
                d = x0.x-ca0.x; p0 += d*d;  d = x0.y-ca0.y; p0 += d*d;  d = x0.z-ca0.z; p0 += d*d;  d = x0.w-ca0.w; p0 += d*d;
                d = x1.x-ca1.x; p0 += d*d;  d = x1.y-ca1.y; p0 += d*d;  d = x1.z-ca1.z; p0 += d*d;  d = x1.w-ca1.w; p0 += d*d;
                d = x0.x-cb0.x; p1 += d*d;  d = x0.y-cb0.y; p1 += d*d;  d = x0.z-cb0.z; p1 += d*d;  d = x0.w-cb0.w; p1 += d*d;
                d = x1.x-cb1.x; p1 += d*d;  d = x1.y-cb1.y; p1 += d*d;  d = x1.z-cb1.z; p1 += d*d;  d = x1.w-cb1.w; p1 += d*d;
                d = x0.x-cc0.x; p2 += d*d;  d = x0.y-cc0.y; p2 += d*d;  d = x0.z-cc0.z; p2 += d*d;  d = x0.w-cc0.w; p2 += d*d;
                d = x1.x-cc1.x; p2 += d*d;  d = x1.y-cc1.y; p2 += d*d;  d = x1.z-cc1.z; p2 += d*d;  d = x1.w-cc1.w; p2 += d*d;
                d = x0.x-cd0.x; p3 += d*d;  d = x0.y-cd0.y; p3 += d*d;  d = x0.z-cd0.z; p3 += d*d;  d = x0.w-cd0.w; p3 += d*d;
                d = x1.x-cd1.x; p3 += d*d;  d = x1.y-cd1.y; p3 += d*d;  d = x1.z-cd1.z; p3 += d*d;  d = x1.w-cd1.w; p3 += d*d;
                #pragma unroll
                for (int s = 1; s < 64; s <<= 1) {
                    p0 += __shfl_xor(p0, s, 64);
                    p1 += __shfl_xor(p1, s, 64);
                    p2 += __shfl_xor(p2, s, 64);
                    p3 += __shfl_xor(p3, s, 64);
                }
                m0v = fminf(m0v, p0); m1v = fminf(m1v, p1);
                m2v = fminf(m2v, p2); m3v = fminf(m3v, p3);
            }
            if (lane < 4 && c0 + lane < nct) {
                float mv = (lane == 0) ? m0v : (lane == 1) ? m1v : (lane == 2) ? m2v : m3v;
                atomicMin((unsigned*)&cand_val[c0 + lane], __float_as_uint(mv));
            }
        }
    }
    if (mode < 0) { __threadfence(); grid.sync(); }

    // ---------- P2: per-batch argmax (redundant) + winners' exact dist rows ----------
    if (mode < 0 || mode == 2) {
        if (blockIdx.x < 782) {
            int item = blockIdx.x;
            int bg = (item / 391) * 4;
            int chunk = item % 391;
            int n = ncand[0]; if (n > 64) n = 64;
            int sp0, sp1, sp2, sp3;
#define WINNER(Q, OUTV) do { float v = -INF_F; int pix = 0x7fffffff; \
            if (lane < n && cand_bat[lane] == bg + (Q)) { v = cand_val[lane]; pix = cand_pix[lane]; } \
            for (int s = 1; s < 64; s <<= 1) { \
                float ov = __shfl_xor(v, s, 64); int oi = __shfl_xor(pix, s, 64); \
                if (ov > v || (ov == v && oi < pix)) { v = ov; pix = oi; } } \
            OUTV = (pix == 0x7fffffff) ? (bg + (Q)) * 1024 : pix; } while (0)
            WINNER(0, sp0); WINNER(1, sp1); WINNER(2, sp2); WINNER(3, sp3);
#undef WINNER
            const float4* s0 = (const float4*)(fv + (size_t)sp0 * 512) + lane * 2;
            const float4* s1 = (const float4*)(fv + (size_t)sp1 * 512) + lane * 2;
            const float4* s2 = (const float4*)(fv + (size_t)sp2 * 512) + lane * 2;
            const float4* s3 = (const float4*)(fv + (size_t)sp3 * 512) + lane * 2;
            float4 ca0 = s0[0], ca1 = s0[1];
            float4 cb0 = s1[0], cb1 = s1[1];
            float4 cc0 = s2[0], cc1 = s2[1];
            float4 cd0 = s3[0], cd1 = s3[1];
            int rbase = chunk * 64 + wid * 16;
            for (int i = 0; i < 16; ++i) {
                int r = rbase + i;
                if (r >= 25000) break;
                const float4* mp = (const float4*)(mb + (size_t)r * 512) + lane * 2;
                float4 x0 = mp[0], x1 = mp[1];
                float d, p0 = 0.f, p1 = 0.f, p2 = 0.f, p3 = 0.f;
                d = x0.x-ca0.x; p0 += d*d;  d = x0.y-ca0.y; p0 += d*d;  d = x0.z-ca0.z; p0 += d*d;  d = x0.w-ca0.w; p0 += d*d;
                d = x1.x-ca1.x; p0 += d*d;  d = x1.y-ca1.y; p0 += d*d;  d = x1.z-ca1.z; p0 += d*d;  d = x1.w-ca1.w; p0 += d*d;
                d = x0.x-cb0.x; p1 += d*d;  d = x0.y-cb0.y; p1 += d*d;  d = x0.z-cb0.z; p1 += d*d;  d = x0.w-cb0.w; p1 += d*d;
                d = x1.x-cb1.x; p1 += d*d;  d = x1.y-cb1.y; p1 += d*d;  d = x1.z-cb1.z; p1 += d*d;  d = x1.w-cb1.w; p1 += d*d;
                d = x0.x-cc0.x; p2 += d*d;  d = x0.y-cc0.y; p2 += d*d;  d = x0.z-cc0.z; p2 += d*d;  d = x0.w-cc0.w; p2 += d*d;
                d = x1.x-cc1.x; p2 += d*d;  d = x1.y-cc1.y; p2 += d*d;  d = x1.z-cc1.z; p2 += d*d;  d = x1.w-cc1.w; p2 += d*d;
                d = x0.x-cd0.x; p3 += d*d;  d = x0.y-cd0.y; p3 += d*d;  d = x0.z-cd0.z; p3 += d*d;  d = x0.w-cd0.w; p3 += d*d;
                d = x1.x-cd1.x; p3 += d*d;  d = x1.y-cd1.y; p3 += d*d;  d = x1.z-cd1.z; p3 += d*d;  d = x1.w-cd1.w; p3 += d*d;
                #pragma unroll
                for (int s = 1; s < 64; s <<= 1) {
                    p0 += __shfl_xor(p0, s, 64);
                    p1 += __shfl_xor(p1, s, 64);
                    p2 += __shfl_xor(p2, s, 64);
                    p3 += __shfl_xor(p3, s, 64);
                }
                if (lane < 4) {
                    float pv = (lane == 0) ? p0 : (lane == 1) ? p1 : (lane == 2) ? p2 : p3;
                    exact_d[(size_t)(bg + lane) * 25000 + r] = pv;
                }
            }
        }
    }
    if (mode < 0) { __threadfence(); grid.sync(); }

    // ---------- P3: top-b (ascending, jax tie order) + softmax (blocks 0..7) ----------
    if (mode < 0 || mode == 3) {
        if (blockIdx.x < 8) {
            int b = blockIdx.x;
            int bval = bp[0]; if (bval > 128) bval = 128; if (bval < 1) bval = 1;
            const float* dv = exact_d + (size_t)b * 25000;
            if (bval <= 16) {
                float tv[16]; int ti[16];
                #pragma unroll
                for (int k = 0; k < 16; ++k) { tv[k] = INF_F; ti[k] = 0x7fffffff; }
                for (int r = t; r < 25000; r += 256) {
                    float cv = dv[r]; int ci = r;
                    #pragma unroll
                    for (int k = 0; k < 16; ++k) {
                        bool better = (cv < tv[k]) || (cv == tv[k] && ci < ti[k]);
                        if (better) {
                            float t1 = tv[k]; tv[k] = cv; cv = t1;
                            int   t2 = ti[k]; ti[k] = ci; ci = t2;
                        }
                    }
                }
                for (int k = 0; k < bval; ++k) {
                    float bv = tv[0]; int bi = ti[0];
                    #pragma unroll
                    for (int s = 1; s < 64; s <<= 1) {
                        float ov = __shfl_xor(bv, s, 64); int oi = __shfl_xor(bi, s, 64);
                        if (ov < bv || (ov == bv && oi < bi)) { bv = ov; bi = oi; }
                    }
                    if (lane == 0) { s_wbv[wid] = bv; s_wbi[wid] = bi; }
                    __syncthreads();
                    if (t == 0) {
                        float fb = s_wbv[0]; int fi = s_wbi[0];
                        for (int w2 = 1; w2 < 4; ++w2)
                            if (s_wbv[w2] < fb || (s_wbv[w2] == fb && s_wbi[w2] < fi)) { fb = s_wbv[w2]; fi = s_wbi[w2]; }
                        s_seld[k] = sqrtf(fb);
                        s_gbv = fb; s_gbi = fi;
                    }
                    __syncthreads();
                    if (tv[0] == s_gbv && ti[0] == s_gbi) {   // unique index -> one thread
                        #pragma unroll
                        for (int k2 = 0; k2 < 15; ++k2) { tv[k2] = tv[k2 + 1]; ti[k2] = ti[k2 + 1]; }
                        tv[15] = INF_F; ti[15] = 0x7fffffff;
                    }
                }
            } else {
                float lastV = -INF_F; int lastI = -1;
                for (int k = 0; k < bval; ++k) {
                    float bv = INF_F; int bi = 0x7fffffff;
                    for (int r = t; r < 25000; r += 256) {
                        float vv = dv[r];
                        bool after = (vv > lastV) || (vv == lastV && r > lastI);
                        if (after && (vv < bv || (vv == bv && r < bi))) { bv = vv; bi = r; }
                    }
                    #pragma unroll
                    for (int s = 1; s < 64; s <<= 1) {
                        float ov = __shfl_xor(bv, s, 64); int oi = __shfl_xor(bi, s, 64);
                        if (ov < bv || (ov == bv && oi < bi)) { bv = ov; bi = oi; }
                    }
                    if (lane == 0) { s_wbv[wid] = bv; s_wbi[wid] = bi; }
                    __syncthreads();
                    if (t == 0) {
                        float fb = s_wbv[0]; int fi = s_wbi[0];
                        for (int w2 = 1; w2 < 4; ++w2)
                            if (s_wbv[w2] < fb || (s_wbv[w2] == fb && s_wbi[w2] < fi)) { fb = s_wbv[w2]; fi = s_wbi[w2]; }
                        s_seld[k] = sqrtf(fb);
                        s_gbv = fb; s_gbi = fi;
                    }
                    __syncthreads();
                    lastV = s_gbv; lastI = s_gbi;
                }
            }
            if (t == 0) {
                float d0 = s_seld[0];
                float img = d0;
                if (bval > 1) {
                    float m = -INF_F;
                    for (int k = 0; k < bval; ++k) m = fmaxf(m, s_seld[k]);
                    float s = 0.f;
                    for (int k = 0; k < bval; ++k) s += expf(s_seld[k] - m);
                    float p0 = expf(s_seld[0] - m) / s;
                    img = d0 * (1.0f - p0);
                }
                out_img[b] = img;
            }
        }
    }
}

extern "C" void kernel_launch(void* const* d_in, const int* in_sizes, int n_in,
                              void* d_out, int out_size, void* d_ws, size_t ws_size,
                              hipStream_t stream) {
    const float* fv = (const float*)d_in[0];   // 8192 x 512
    const float* mb = (const float*)d_in[1];   // 25000 x 512
    const int*   bp = (const int*)d_in[2];     // scalar b
    float* out = (float*)d_out;                // [0..8191]=pixel_scores, [8192..8199]=image_scores

    char* w = (char*)d_ws;                     // ~35 MB total (proven footprint)
    unsigned short* fvb = (unsigned short*)w;                       // 8,388,608 B
    unsigned short* mbb = (unsigned short*)(w + 8388608);           // 25,600,000 B
    size_t o = 8388608 + 25600000;
    float* fnorm    = (float*)(w + o); o += 32768;
    float* mnorm    = (float*)(w + o); o += 100352;
    float* ps_sq    = (float*)(w + o); o += 32768;
    int*   ncand    = (int*)(w + o);   o += 256;
    int*   cand_pix = (int*)(w + o);   o += 256;
    int*   cand_bat = (int*)(w + o);   o += 256;
    float* cand_val = (float*)(w + o); o += 256;
    int*   sel_unused = (int*)(w + o); o += 256;
    float* exact_d  = (float*)(w + o); o += 800000;    // 8 x 25000 fp32
    (void)sel_unused;

    k_conv<<<8298, 256, 0, stream>>>(fv, mb, fvb, mbb, fnorm, mnorm, ps_sq, ncand, cand_val);
    k_gemm_min<<<12544, 256, 0, stream>>>(fvb, mbb, fnorm, mnorm, ps_sq);

    float* out0 = out;
    float* oimg = out + 8192;
    int mode = -1;
    const float* fv_a = fv; const float* mb_a = mb; const float* ps_a = ps_sq;
    const int* bp_a = bp;
    void* args[] = { (void*)&fv_a, (void*)&mb_a, (void*)&ps_a, (void*)&out0,
                     (void*)&ncand, (void*)&cand_pix, (void*)&cand_bat, (void*)&cand_val,
                     (void*)&exact_d, (void*)&bp_a, (void*)&oimg, (void*)&mode };
    hipError_t e = hipLaunchCooperativeKernel((const void*)k_tail, dim3(1024), dim3(256),
                                              args, 0, stream);
    if (e != hipSuccess) {
        (void)hipGetLastError();   // clear sticky error; fall back to 4 plain launches
        for (int m = 0; m < 4; ++m)
            k_tail<<<1024, 256, 0, stream>>>(fv, mb, ps_sq, out0, ncand, cand_pix, cand_bat,
                                             cand_val, exact_d, bp, oimg, m);
    }
}

// Round 9
// 490.001 us; speedup vs baseline: 2.3073x; 2.3073x over previous
//
#include <hip/hip_runtime.h>
#include <hip/hip_bf16.h>

typedef __attribute__((ext_vector_type(8))) short short8;
typedef __attribute__((ext_vector_type(4))) float f32x4;

#define INF_F 3.4e38f

__device__ __forceinline__ void gload16(const void* g, void* l) {
    __builtin_amdgcn_global_load_lds((const __attribute__((address_space(1))) unsigned*)g,
                                     (__attribute__((address_space(3))) unsigned*)l, 16, 0, 0);
}

// ---------------- fp32 -> bf16 + row norms (512 cols) for BOTH fv and mb, + init ----------------
__global__ void k_conv(const float* __restrict__ fv, const float* __restrict__ mbp,
                       unsigned short* __restrict__ fvb, unsigned short* __restrict__ mbb,
                       float* __restrict__ fnorm, float* __restrict__ mnorm,
                       float* ps_sq, int* ncand, float* cand_val) {
    int t = threadIdx.x, wid = t >> 6, lane = t & 63;
    if (blockIdx.x == 0) {
        if (t == 0) ncand[0] = 0;
        if (t < 64) ((unsigned*)cand_val)[t] = 0x7f800000u;
    }
    int row = blockIdx.x * 4 + wid;
    const float* in; unsigned short* outb; float* norm; int r;
    if (row < 8192) {
        in = fv; outb = fvb; norm = fnorm; r = row;
        if (lane == 0) ((unsigned*)ps_sq)[row] = 0x7f800000u;   // +inf init
    } else if (row < 33192) {
        in = mbp; outb = mbb; norm = mnorm; r = row - 8192;
    } else return;
    const float4* p = (const float4*)(in + (size_t)r * 512) + lane * 2;
    float4 a = p[0], b = p[1];
    float n = a.x*a.x + a.y*a.y + a.z*a.z + a.w*a.w
            + b.x*b.x + b.y*b.y + b.z*b.z + b.w*b.w;
    float vals[8] = {a.x, a.y, a.z, a.w, b.x, b.y, b.z, b.w};
    unsigned short h[8];
    #pragma unroll
    for (int e = 0; e < 8; ++e) {
        unsigned u = __float_as_uint(vals[e]);
        h[e] = (unsigned short)((u + 0x7fffu + ((u >> 16) & 1u)) >> 16);  // RNE
    }
    *(uint4*)(outb + (size_t)r * 512 + lane * 8) = *(uint4*)h;
    #pragma unroll
    for (int s = 1; s < 64; s <<= 1) n += __shfl_xor(n, s, 64);
    if (lane == 0) norm[r] = n;
}

// ---------------- fused GEMM + per-row min (R5/R7-proven m97 structure) ----------------
__global__ __launch_bounds__(256, 2)
void k_gemm_min(const unsigned short* __restrict__ A, const unsigned short* __restrict__ B,
                const float* __restrict__ fnorm, const float* __restrict__ mnorm,
                float* __restrict__ ps_sq) {
    __shared__ unsigned short At[128 * 64];
    __shared__ unsigned short Bt[128 * 64];
    int tid = threadIdx.x, wid = tid >> 6, lane = tid & 63;
    int bid = blockIdx.x;
    int pos = bid >> 3;
    int rb = ((bid & 7) << 3) | (pos & 7);   // 0..63
    int cb = pos >> 3;                        // 0..195
    int brow = rb * 128, bcol = cb * 128;
    int wm = (wid >> 1) * 64, wn = (wid & 1) * 64;

    f32x4 acc[4][4] = {};
    int lr = lane >> 3;
    int lkswz = ((lane & 7) ^ lr) * 8;        // pre-swizzled source column (elems)

    for (int k0 = 0; k0 < 512; k0 += 64) {
        #pragma unroll
        for (int c = 0; c < 4; ++c) {
            int ch = wid + c * 4;
            int row = ch * 8 + lr;
            gload16(A + (size_t)(brow + row) * 512 + k0 + lkswz, &At[ch * 512]);
            int srow = bcol + row; if (srow > 24999) srow = 24999;
            gload16(B + (size_t)srow * 512 + k0 + lkswz, &Bt[ch * 512]);
        }
        __syncthreads();
        #pragma unroll
        for (int kk = 0; kk < 2; ++kk) {
            short8 af[4], bf[4];
            int ko = kk * 32 + (lane >> 4) * 8;
            #pragma unroll
            for (int mi = 0; mi < 4; ++mi) {
                int r = wm + mi * 16 + (lane & 15);
                af[mi] = *(const short8*)&At[r * 64 + (ko ^ ((r & 7) << 3))];
            }
            #pragma unroll
            for (int ni = 0; ni < 4; ++ni) {
                int r = wn + ni * 16 + (lane & 15);
                bf[ni] = *(const short8*)&Bt[r * 64 + (ko ^ ((r & 7) << 3))];
            }
            #pragma unroll
            for (int mi = 0; mi < 4; ++mi)
                #pragma unroll
                for (int ni = 0; ni < 4; ++ni)
                    acc[mi][ni] = __builtin_amdgcn_mfma_f32_16x16x32_bf16(af[mi], bf[ni], acc[mi][ni], 0, 0, 0);
        }
        __syncthreads();
    }

    float mnv[4];
    #pragma unroll
    for (int ni = 0; ni < 4; ++ni) {
        int col = bcol + wn + ni * 16 + (lane & 15);
        mnv[ni] = (col < 25000) ? mnorm[col] : INF_F;
    }
    #pragma unroll
    for (int mi = 0; mi < 4; ++mi) {
        #pragma unroll
        for (int r = 0; r < 4; ++r) {
            float v = INF_F;
            #pragma unroll
            for (int ni = 0; ni < 4; ++ni) v = fminf(v, mnv[ni] - 2.0f * acc[mi][ni][r]);
            #pragma unroll
            for (int s = 1; s < 16; s <<= 1) v = fminf(v, __shfl_xor(v, s, 64));
            if ((lane & 15) == 0) {
                int row = brow + wm + mi * 16 + (lane >> 4) * 4 + r;
                float sq = v + fnorm[row];
                atomicMin((unsigned*)&ps_sq[row], __float_as_uint(sq));
            }
        }
    }
}

// ---------------- out0 + per-batch candidate gather ----------------
__global__ void k_cand(const float* __restrict__ ps_sq, float* __restrict__ out0,
                       int* ncand, int* cand_pix, int* cand_batch) {
    __shared__ float smax[4];
    __shared__ int scnt;
    int b = blockIdx.x, t = threadIdx.x, wid = t >> 6, lane = t & 63;
    const float* base = ps_sq + b * 1024;
    float v[4]; float m = -INF_F;
    #pragma unroll
    for (int i = 0; i < 4; ++i) {
        v[i] = base[t + i * 256];
        out0[b * 1024 + t + i * 256] = sqrtf(fmaxf(v[i], 0.0f));
        m = fmaxf(m, v[i]);
    }
    #pragma unroll
    for (int s = 1; s < 64; s <<= 1) m = fmaxf(m, __shfl_xor(m, s, 64));
    if (lane == 0) smax[wid] = m;
    if (t == 0) scnt = 0;
    __syncthreads();
    float bm = fmaxf(fmaxf(smax[0], smax[1]), fmaxf(smax[2], smax[3]));
    #pragma unroll
    for (int i = 0; i < 4; ++i) {
        if (v[i] >= bm - 8.0f) {            // margin >> 2x worst-case bf16 dot error
            int s = atomicAdd(&scnt, 1);
            if (s < 8) {
                int g = atomicAdd(ncand, 1);
                if (g < 64) { cand_pix[g] = b * 1024 + t + i * 256; cand_batch[g] = b; }
            }
        }
    }
}

// ---------------- exact fp32 min-dist, 4 cands/block, pipelined branchless row loop ----------------
__global__ __launch_bounds__(256, 4)
void k_score(const float* __restrict__ fv, const float* __restrict__ mb,
             const int* __restrict__ ncand, const int* __restrict__ cand_pix,
             float* __restrict__ cand_val) {
    int nct = ncand[0]; if (nct > 64) nct = 64;
    int c0 = blockIdx.y * 4;
    if (c0 >= nct) return;
    int t = threadIdx.x, wid = t >> 6, lane = t & 63;

    int p0i = cand_pix[c0];
    int p1i = cand_pix[c0 + 1 < nct ? c0 + 1 : c0];
    int p2i = cand_pix[c0 + 2 < nct ? c0 + 2 : c0];
    int p3i = cand_pix[c0 + 3 < nct ? c0 + 3 : c0];
    const float4* s0 = (const float4*)(fv + (size_t)p0i * 512) + lane * 2;
    const float4* s1 = (const float4*)(fv + (size_t)p1i * 512) + lane * 2;
    const float4* s2 = (const float4*)(fv + (size_t)p2i * 512) + lane * 2;
    const float4* s3 = (const float4*)(fv + (size_t)p3i * 512) + lane * 2;
    float4 ca0 = s0[0], ca1 = s0[1];
    float4 cb0 = s1[0], cb1 = s1[1];
    float4 cc0 = s2[0], cc1 = s2[1];
    float4 cd0 = s3[0], cd1 = s3[1];

    float m0v = INF_F, m1v = INF_F, m2v = INF_F, m3v = INF_F;
    int rbase = blockIdx.x * 64 + wid * 16;
    #pragma unroll 4
    for (int i = 0; i < 16; ++i) {
        int r = rbase + i;
        int rc = r < 24999 ? r : 24999;                 // clamp addr; predicate result
        const float4* mp = (const float4*)(mb + (size_t)rc * 512) + lane * 2;
        float4 x0 = mp[0], x1 = mp[1];
        float d, p0 = 0.f, p1 = 0.f, p2 = 0.f, p3 = 0.f;
        d = x0.x-ca0.x; p0 += d*d;  d = x0.y-ca0.y; p0 += d*d;  d = x0.z-ca0.z; p0 += d*d;  d = x0.w-ca0.w; p0 += d*d;
        d = x1.x-ca1.x; p0 += d*d;  d = x1.y-ca1.y; p0 += d*d;  d = x1.z-ca1.z; p0 += d*d;  d = x1.w-ca1.w; p0 += d*d;
        d = x0.x-cb0.x; p1 += d*d;  d = x0.y-cb0.y; p1 += d*d;  d = x0.z-cb0.z; p1 += d*d;  d = x0.w-cb0.w; p1 += d*d;
        d = x1.x-cb1.x; p1 += d*d;  d = x1.y-cb1.y; p1 += d*d;  d = x1.z-cb1.z; p1 += d*d;  d = x1.w-cb1.w; p1 += d*d;
        d = x0.x-cc0.x; p2 += d*d;  d = x0.y-cc0.y; p2 += d*d;  d = x0.z-cc0.z; p2 += d*d;  d = x0.w-cc0.w; p2 += d*d;
        d = x1.x-cc1.x; p2 += d*d;  d = x1.y-cc1.y; p2 += d*d;  d = x1.z-cc1.z; p2 += d*d;  d = x1.w-cc1.w; p2 += d*d;
        d = x0.x-cd0.x; p3 += d*d;  d = x0.y-cd0.y; p3 += d*d;  d = x0.z-cd0.z; p3 += d*d;  d = x0.w-cd0.w; p3 += d*d;
        d = x1.x-cd1.x; p3 += d*d;  d = x1.y-cd1.y; p3 += d*d;  d = x1.z-cd1.z; p3 += d*d;  d = x1.w-cd1.w; p3 += d*d;
        #pragma unroll
        for (int s = 1; s < 64; s <<= 1) {
            p0 += __shfl_xor(p0, s, 64);
            p1 += __shfl_xor(p1, s, 64);
            p2 += __shfl_xor(p2, s, 64);
            p3 += __shfl_xor(p3, s, 64);
        }
        bool ok = (r < 25000);
        m0v = fminf(m0v, ok ? p0 : INF_F); m1v = fminf(m1v, ok ? p1 : INF_F);
        m2v = fminf(m2v, ok ? p2 : INF_F); m3v = fminf(m3v, ok ? p3 : INF_F);
    }
    if (lane < 4 && c0 + lane < nct) {
        float mv = (lane == 0) ? m0v : (lane == 1) ? m1v : (lane == 2) ? m2v : m3v;
        atomicMin((unsigned*)&cand_val[c0 + lane], __float_as_uint(mv));
    }
}

// ---------------- winners' exact distances; argmax folded in; pipelined row loop ----------------
__global__ __launch_bounds__(256, 4)
void k_dists4(const float* __restrict__ fv, const float* __restrict__ mb,
              const int* __restrict__ ncand, const int* __restrict__ cand_pix,
              const int* __restrict__ cand_batch, const float* __restrict__ cand_val,
              float* __restrict__ exact_d) {
    int bg = blockIdx.y * 4;                 // batch group: 0..3 or 4..7
    int t = threadIdx.x, wid = t >> 6, lane = t & 63;
    int n = ncand[0]; if (n > 64) n = 64;

    int sp0, sp1, sp2, sp3;
#define WINNER(Q, OUTV) do { float v = -INF_F; int pix = 0x7fffffff; \
    if (lane < n && cand_batch[lane] == bg + (Q)) { v = cand_val[lane]; pix = cand_pix[lane]; } \
    _Pragma("unroll") \
    for (int s = 1; s < 64; s <<= 1) { \
        float ov = __shfl_xor(v, s, 64); int oi = __shfl_xor(pix, s, 64); \
        if (ov > v || (ov == v && oi < pix)) { v = ov; pix = oi; } } \
    OUTV = (pix == 0x7fffffff) ? (bg + (Q)) * 1024 : pix; } while (0)
    WINNER(0, sp0); WINNER(1, sp1); WINNER(2, sp2); WINNER(3, sp3);
#undef WINNER

    const float4* s0 = (const float4*)(fv + (size_t)sp0 * 512) + lane * 2;
    const float4* s1 = (const float4*)(fv + (size_t)sp1 * 512) + lane * 2;
    const float4* s2 = (const float4*)(fv + (size_t)sp2 * 512) + lane * 2;
    const float4* s3 = (const float4*)(fv + (size_t)sp3 * 512) + lane * 2;
    float4 ca0 = s0[0], ca1 = s0[1];
    float4 cb0 = s1[0], cb1 = s1[1];
    float4 cc0 = s2[0], cc1 = s2[1];
    float4 cd0 = s3[0], cd1 = s3[1];

    int rbase = blockIdx.x * 64 + wid * 16;
    #pragma unroll 4
    for (int i = 0; i < 16; ++i) {
        int r = rbase + i;
        int rc = r < 24999 ? r : 24999;
        const float4* mp = (const float4*)(mb + (size_t)rc * 512) + lane * 2;
        float4 x0 = mp[0], x1 = mp[1];
        float d, p0 = 0.f, p1 = 0.f, p2 = 0.f, p3 = 0.f;
        d = x0.x-ca0.x; p0 += d*d;  d = x0.y-ca0.y; p0 += d*d;  d = x0.z-ca0.z; p0 += d*d;  d = x0.w-ca0.w; p0 += d*d;
        d = x1.x-ca1.x; p0 += d*d;  d = x1.y-ca1.y; p0 += d*d;  d = x1.z-ca1.z; p0 += d*d;  d = x1.w-ca1.w; p0 += d*d;
        d = x0.x-cb0.x; p1 += d*d;  d = x0.y-cb0.y; p1 += d*d;  d = x0.z-cb0.z; p1 += d*d;  d = x0.w-cb0.w; p1 += d*d;
        d = x1.x-cb1.x; p1 += d*d;  d = x1.y-cb1.y; p1 += d*d;  d = x1.z-cb1.z; p1 += d*d;  d = x1.w-cb1.w; p1 += d*d;
        d = x0.x-cc0.x; p2 += d*d;  d = x0.y-cc0.y; p2 += d*d;  d = x0.z-cc0.z; p2 += d*d;  d = x0.w-cc0.w; p2 += d*d;
        d = x1.x-cc1.x; p2 += d*d;  d = x1.y-cc1.y; p2 += d*d;  d = x1.z-cc1.z; p2 += d*d;  d = x1.w-cc1.w; p2 += d*d;
        d = x0.x-cd0.x; p3 += d*d;  d = x0.y-cd0.y; p3 += d*d;  d = x0.z-cd0.z; p3 += d*d;  d = x0.w-cd0.w; p3 += d*d;
        d = x1.x-cd1.x; p3 += d*d;  d = x1.y-cd1.y; p3 += d*d;  d = x1.z-cd1.z; p3 += d*d;  d = x1.w-cd1.w; p3 += d*d;
        #pragma unroll
        for (int s = 1; s < 64; s <<= 1) {
            p0 += __shfl_xor(p0, s, 64);
            p1 += __shfl_xor(p1, s, 64);
            p2 += __shfl_xor(p2, s, 64);
            p3 += __shfl_xor(p3, s, 64);
        }
        if (lane < 4 && r < 25000) {
            float pv = (lane == 0) ? p0 : (lane == 1) ? p1 : (lane == 2) ? p2 : p3;
            exact_d[(size_t)(bg + lane) * 25000 + r] = pv;
        }
    }
}

// ---------------- single-pass top-b (ascending dist, jax tie order) + softmax ----------------
__global__ __launch_bounds__(1024)
void k_final(const float* __restrict__ exact_d, const int* __restrict__ bptr,
             float* __restrict__ out_img) {
    __shared__ float wbv[16]; __shared__ int wbi[16];
    __shared__ float seld[128];
    __shared__ float gbv_s; __shared__ int gbi_s;
    int b = blockIdx.x, t = threadIdx.x, wid = t >> 6, lane = t & 63;
    int bval = bptr[0]; if (bval > 128) bval = 128; if (bval < 1) bval = 1;
    const float* dv = exact_d + (size_t)b * 25000;

    if (bval <= 16) {
        float tv[16]; int ti[16];
        #pragma unroll
        for (int k = 0; k < 16; ++k) { tv[k] = INF_F; ti[k] = 0x7fffffff; }
        for (int r = t; r < 25000; r += 1024) {
            float cv = dv[r]; int ci = r;
            #pragma unroll
            for (int k = 0; k < 16; ++k) {
                bool better = (cv < tv[k]) || (cv == tv[k] && ci < ti[k]);
                if (better) {
                    float t1 = tv[k]; tv[k] = cv; cv = t1;
                    int   t2 = ti[k]; ti[k] = ci; ci = t2;
                }
            }
        }
        for (int k = 0; k < bval; ++k) {
            float bv = tv[0]; int bi = ti[0];
            #pragma unroll
            for (int s = 1; s < 64; s <<= 1) {
                float ov = __shfl_xor(bv, s, 64); int oi = __shfl_xor(bi, s, 64);
                if (ov < bv || (ov == bv && oi < bi)) { bv = ov; bi = oi; }
            }
            if (lane == 0) { wbv[wid] = bv; wbi[wid] = bi; }
            __syncthreads();
            if (t == 0) {
                float fb = wbv[0]; int fi = wbi[0];
                for (int w2 = 1; w2 < 16; ++w2)
                    if (wbv[w2] < fb || (wbv[w2] == fb && wbi[w2] < fi)) { fb = wbv[w2]; fi = wbi[w2]; }
                seld[k] = sqrtf(fb);
                gbv_s = fb; gbi_s = fi;
            }
            __syncthreads();
            if (tv[0] == gbv_s && ti[0] == gbi_s) {       // unique index -> exactly one thread
                #pragma unroll
                for (int k2 = 0; k2 < 15; ++k2) { tv[k2] = tv[k2 + 1]; ti[k2] = ti[k2 + 1]; }
                tv[15] = INF_F; ti[15] = 0x7fffffff;
            }
        }
    } else {
        float lastV = -INF_F; int lastI = -1;
        for (int k = 0; k < bval; ++k) {
            float bv = INF_F; int bi = 0x7fffffff;
            for (int r = t; r < 25000; r += 1024) {
                float vv = dv[r];
                bool after = (vv > lastV) || (vv == lastV && r > lastI);
                if (after && (vv < bv || (vv == bv && r < bi))) { bv = vv; bi = r; }
            }
            #pragma unroll
            for (int s = 1; s < 64; s <<= 1) {
                float ov = __shfl_xor(bv, s, 64); int oi = __shfl_xor(bi, s, 64);
                if (ov < bv || (ov == bv && oi < bi)) { bv = ov; bi = oi; }
            }
            if (lane == 0) { wbv[wid] = bv; wbi[wid] = bi; }
            __syncthreads();
            if (t == 0) {
                float fb = wbv[0]; int fi = wbi[0];
                for (int w2 = 1; w2 < 16; ++w2)
                    if (wbv[w2] < fb || (wbv[w2] == fb && wbi[w2] < fi)) { fb = wbv[w2]; fi = wbi[w2]; }
                seld[k] = sqrtf(fb);
                gbv_s = fb; gbi_s = fi;
            }
            __syncthreads();
            lastV = gbv_s; lastI = gbi_s;
        }
    }

    if (t == 0) {
        float d0 = seld[0];
        float img = d0;
        if (bval > 1) {
            float m = -INF_F;
            for (int k = 0; k < bval; ++k) m = fmaxf(m, seld[k]);
            float s = 0.f;
            for (int k = 0; k < bval; ++k) s += expf(seld[k] - m);
            float p0 = expf(seld[0] - m) / s;
            img = d0 * (1.0f - p0);
        }
        out_img[b] = img;
    }
}

extern "C" void kernel_launch(void* const* d_in, const int* in_sizes, int n_in,
                              void* d_out, int out_size, void* d_ws, size_t ws_size,
                              hipStream_t stream) {
    const float* fv = (const float*)d_in[0];   // 8192 x 512
    const float* mb = (const float*)d_in[1];   // 25000 x 512
    const int*   bp = (const int*)d_in[2];     // scalar b
    float* out = (float*)d_out;                // [0..8191]=pixel_scores, [8192..8199]=image_scores

    char* w = (char*)d_ws;                     // ~35 MB total (proven footprint)
    unsigned short* fvb = (unsigned short*)w;                       // 8,388,608 B
    unsigned short* mbb = (unsigned short*)(w + 8388608);           // 25,600,000 B
    size_t o = 8388608 + 25600000;
    float* fnorm    = (float*)(w + o); o += 32768;
    float* mnorm    = (float*)(w + o); o += 100352;
    float* ps_sq    = (float*)(w + o); o += 32768;
    int*   ncand    = (int*)(w + o);   o += 256;
    int*   cand_pix = (int*)(w + o);   o += 256;
    int*   cand_bat = (int*)(w + o);   o += 256;
    float* cand_val = (float*)(w + o); o += 256;
    int*   sel_unused = (int*)(w + o); o += 256;
    float* exact_d  = (float*)(w + o); o += 800000;    // 8 x 25000 fp32
    (void)sel_unused;

    k_conv<<<8298, 256, 0, stream>>>(fv, mb, fvb, mbb, fnorm, mnorm, ps_sq, ncand, cand_val);
    k_gemm_min<<<12544, 256, 0, stream>>>(fvb, mbb, fnorm, mnorm, ps_sq);
    k_cand<<<8, 256, 0, stream>>>(ps_sq, out, ncand, cand_pix, cand_bat);
    k_score<<<dim3(391, 16), 256, 0, stream>>>(fv, mb, ncand, cand_pix, cand_val);
    k_dists4<<<dim3(391, 2), 256, 0, stream>>>(fv, mb, ncand, cand_pix, cand_bat, cand_val, exact_d);
    k_final<<<8, 1024, 0, stream>>>(exact_d, bp, out + 8192);
}

// Round 10
// 477.293 us; speedup vs baseline: 2.3687x; 1.0266x over previous
//
#include <hip/hip_runtime.h>
#include <hip/hip_bf16.h>

typedef __attribute__((ext_vector_type(8))) short short8;
typedef __attribute__((ext_vector_type(4))) float f32x4;

#define INF_F 3.4e38f

__device__ __forceinline__ void gload16(const void* g, void* l) {
    __builtin_amdgcn_global_load_lds((const __attribute__((address_space(1))) unsigned*)g,
                                     (__attribute__((address_space(3))) unsigned*)l, 16, 0, 0);
}

__device__ __forceinline__ float dot4(float4 a, float4 b) {
    return a.x*b.x + a.y*b.y + a.z*b.z + a.w*b.w;
}

// ---------------- fp32 -> bf16 + row norms (512 cols) for BOTH fv and mb, + init ----------------
__global__ void k_conv(const float* __restrict__ fv, const float* __restrict__ mbp,
                       unsigned short* __restrict__ fvb, unsigned short* __restrict__ mbb,
                       float* __restrict__ fnorm, float* __restrict__ mnorm,
                       float* ps_sq, int* ncand, float* cand_val) {
    int t = threadIdx.x, wid = t >> 6, lane = t & 63;
    if (blockIdx.x == 0) {
        if (t == 0) ncand[0] = 0;
        if (t < 64) ((unsigned*)cand_val)[t] = 0x7f800000u;
    }
    int row = blockIdx.x * 4 + wid;
    const float* in; unsigned short* outb; float* norm; int r;
    if (row < 8192) {
        in = fv; outb = fvb; norm = fnorm; r = row;
        if (lane == 0) ((unsigned*)ps_sq)[row] = 0x7f800000u;   // +inf init
    } else if (row < 33192) {
        in = mbp; outb = mbb; norm = mnorm; r = row - 8192;
    } else return;
    const float4* p = (const float4*)(in + (size_t)r * 512) + lane * 2;
    float4 a = p[0], b = p[1];
    float n = a.x*a.x + a.y*a.y + a.z*a.z + a.w*a.w
            + b.x*b.x + b.y*b.y + b.z*b.z + b.w*b.w;
    float vals[8] = {a.x, a.y, a.z, a.w, b.x, b.y, b.z, b.w};
    unsigned short h[8];
    #pragma unroll
    for (int e = 0; e < 8; ++e) {
        unsigned u = __float_as_uint(vals[e]);
        h[e] = (unsigned short)((u + 0x7fffu + ((u >> 16) & 1u)) >> 16);  // RNE
    }
    *(uint4*)(outb + (size_t)r * 512 + lane * 8) = *(uint4*)h;
    #pragma unroll
    for (int s = 1; s < 64; s <<= 1) n += __shfl_xor(n, s, 64);
    if (lane == 0) norm[r] = n;
}

// ---------------- fused GEMM + per-row min (R5/R7-proven m97 structure) ----------------
__global__ __launch_bounds__(256, 2)
void k_gemm_min(const unsigned short* __restrict__ A, const unsigned short* __restrict__ B,
                const float* __restrict__ fnorm, const float* __restrict__ mnorm,
                float* __restrict__ ps_sq) {
    __shared__ unsigned short At[128 * 64];
    __shared__ unsigned short Bt[128 * 64];
    int tid = threadIdx.x, wid = tid >> 6, lane = tid & 63;
    int bid = blockIdx.x;
    int pos = bid >> 3;
    int rb = ((bid & 7) << 3) | (pos & 7);   // 0..63
    int cb = pos >> 3;                        // 0..195
    int brow = rb * 128, bcol = cb * 128;
    int wm = (wid >> 1) * 64, wn = (wid & 1) * 64;

    f32x4 acc[4][4] = {};
    int lr = lane >> 3;
    int lkswz = ((lane & 7) ^ lr) * 8;        // pre-swizzled source column (elems)

    for (int k0 = 0; k0 < 512; k0 += 64) {
        #pragma unroll
        for (int c = 0; c < 4; ++c) {
            int ch = wid + c * 4;
            int row = ch * 8 + lr;
            gload16(A + (size_t)(brow + row) * 512 + k0 + lkswz, &At[ch * 512]);
            int srow = bcol + row; if (srow > 24999) srow = 24999;
            gload16(B + (size_t)srow * 512 + k0 + lkswz, &Bt[ch * 512]);
        }
        __syncthreads();
        #pragma unroll
        for (int kk = 0; kk < 2; ++kk) {
            short8 af[4], bf[4];
            int ko = kk * 32 + (lane >> 4) * 8;
            #pragma unroll
            for (int mi = 0; mi < 4; ++mi) {
                int r = wm + mi * 16 + (lane & 15);
                af[mi] = *(const short8*)&At[r * 64 + (ko ^ ((r & 7) << 3))];
            }
            #pragma unroll
            for (int ni = 0; ni < 4; ++ni) {
                int r = wn + ni * 16 + (lane & 15);
                bf[ni] = *(const short8*)&Bt[r * 64 + (ko ^ ((r & 7) << 3))];
            }
            #pragma unroll
            for (int mi = 0; mi < 4; ++mi)
                #pragma unroll
                for (int ni = 0; ni < 4; ++ni)
                    acc[mi][ni] = __builtin_amdgcn_mfma_f32_16x16x32_bf16(af[mi], bf[ni], acc[mi][ni], 0, 0, 0);
        }
        __syncthreads();
    }

    float mnv[4];
    #pragma unroll
    for (int ni = 0; ni < 4; ++ni) {
        int col = bcol + wn + ni * 16 + (lane & 15);
        mnv[ni] = (col < 25000) ? mnorm[col] : INF_F;
    }
    #pragma unroll
    for (int mi = 0; mi < 4; ++mi) {
        #pragma unroll
        for (int r = 0; r < 4; ++r) {
            float v = INF_F;
            #pragma unroll
            for (int ni = 0; ni < 4; ++ni) v = fminf(v, mnv[ni] - 2.0f * acc[mi][ni][r]);
            #pragma unroll
            for (int s = 1; s < 16; s <<= 1) v = fminf(v, __shfl_xor(v, s, 64));
            if ((lane & 15) == 0) {
                int row = brow + wm + mi * 16 + (lane >> 4) * 4 + r;
                float sq = v + fnorm[row];
                atomicMin((unsigned*)&ps_sq[row], __float_as_uint(sq));
            }
        }
    }
}

// ---------------- out0 + per-batch candidate gather ----------------
__global__ void k_cand(const float* __restrict__ ps_sq, float* __restrict__ out0,
                       int* ncand, int* cand_pix, int* cand_batch) {
    __shared__ float smax[4];
    __shared__ int scnt;
    int b = blockIdx.x, t = threadIdx.x, wid = t >> 6, lane = t & 63;
    const float* base = ps_sq + b * 1024;
    float v[4]; float m = -INF_F;
    #pragma unroll
    for (int i = 0; i < 4; ++i) {
        v[i] = base[t + i * 256];
        out0[b * 1024 + t + i * 256] = sqrtf(fmaxf(v[i], 0.0f));
        m = fmaxf(m, v[i]);
    }
    #pragma unroll
    for (int s = 1; s < 64; s <<= 1) m = fmaxf(m, __shfl_xor(m, s, 64));
    if (lane == 0) smax[wid] = m;
    if (t == 0) scnt = 0;
    __syncthreads();
    float bm = fmaxf(fmaxf(smax[0], smax[1]), fmaxf(smax[2], smax[3]));
    #pragma unroll
    for (int i = 0; i < 4; ++i) {
        if (v[i] >= bm - 8.0f) {            // margin >> 2x worst-case bf16 dot error
            int s = atomicAdd(&scnt, 1);
            if (s < 8) {
                int g = atomicAdd(ncand, 1);
                if (g < 64) { cand_pix[g] = b * 1024 + t + i * 256; cand_batch[g] = b; }
            }
        }
    }
}

// ---------------- exact min-dist, dot-form, 32-lane row groups (5-step reduce) ----------------
// lane: half = lane>>5 selects row parity; j = lane&31 owns elems [16j,16j+16).
__global__ __launch_bounds__(256, 2)
void k_score(const float* __restrict__ fv, const float* __restrict__ mb,
             const float* __restrict__ fnorm, const float* __restrict__ mnorm,
             const int* __restrict__ ncand, const int* __restrict__ cand_pix,
             float* __restrict__ cand_val) {
    int nct = ncand[0]; if (nct > 64) nct = 64;
    int c0 = blockIdx.y * 4;
    if (c0 >= nct) return;
    int t = threadIdx.x, wid = t >> 6, lane = t & 63;
    int half = lane >> 5, j = lane & 31;

    int p0i = cand_pix[c0];
    int p1i = cand_pix[c0 + 1 < nct ? c0 + 1 : c0];
    int p2i = cand_pix[c0 + 2 < nct ? c0 + 2 : c0];
    int p3i = cand_pix[c0 + 3 < nct ? c0 + 3 : c0];
    const float4* s0 = (const float4*)(fv + (size_t)p0i * 512 + 16 * j);
    const float4* s1 = (const float4*)(fv + (size_t)p1i * 512 + 16 * j);
    const float4* s2 = (const float4*)(fv + (size_t)p2i * 512 + 16 * j);
    const float4* s3 = (const float4*)(fv + (size_t)p3i * 512 + 16 * j);
    float4 a0 = s0[0], a1 = s0[1], a2 = s0[2], a3 = s0[3];
    float4 b0 = s1[0], b1 = s1[1], b2 = s1[2], b3 = s1[3];
    float4 g0 = s2[0], g1 = s2[1], g2 = s2[2], g3 = s2[3];
    float4 h0 = s3[0], h1 = s3[1], h2 = s3[2], h3 = s3[3];
    float fn0 = fnorm[p0i], fn1 = fnorm[p1i], fn2 = fnorm[p2i], fn3 = fnorm[p3i];

    float m0v = INF_F, m1v = INF_F, m2v = INF_F, m3v = INF_F;
    int rbase = blockIdx.x * 64 + wid * 16;
    #pragma unroll 2
    for (int i = 0; i < 8; ++i) {
        int r = rbase + i * 2 + half;
        int rc = r < 24999 ? r : 24999;
        const float4* mp = (const float4*)(mb + (size_t)rc * 512 + 16 * j);
        float4 x0 = mp[0], x1 = mp[1], x2 = mp[2], x3 = mp[3];
        float q0 = dot4(x0,a0) + dot4(x1,a1) + dot4(x2,a2) + dot4(x3,a3);
        float q1 = dot4(x0,b0) + dot4(x1,b1) + dot4(x2,b2) + dot4(x3,b3);
        float q2 = dot4(x0,g0) + dot4(x1,g1) + dot4(x2,g2) + dot4(x3,g3);
        float q3 = dot4(x0,h0) + dot4(x1,h1) + dot4(x2,h2) + dot4(x3,h3);
        #pragma unroll
        for (int s = 1; s < 32; s <<= 1) {     // 5-step, stays within 32-lane group
            q0 += __shfl_xor(q0, s, 64);
            q1 += __shfl_xor(q1, s, 64);
            q2 += __shfl_xor(q2, s, 64);
            q3 += __shfl_xor(q3, s, 64);
        }
        float mnr = mnorm[rc];
        bool ok = (r < 25000);
        float p0 = fn0 + mnr - 2.0f * q0;
        float p1 = fn1 + mnr - 2.0f * q1;
        float p2 = fn2 + mnr - 2.0f * q2;
        float p3 = fn3 + mnr - 2.0f * q3;
        m0v = fminf(m0v, ok ? p0 : INF_F); m1v = fminf(m1v, ok ? p1 : INF_F);
        m2v = fminf(m2v, ok ? p2 : INF_F); m3v = fminf(m3v, ok ? p3 : INF_F);
    }
    // merge even/odd row halves
    m0v = fminf(m0v, __shfl_xor(m0v, 32, 64));
    m1v = fminf(m1v, __shfl_xor(m1v, 32, 64));
    m2v = fminf(m2v, __shfl_xor(m2v, 32, 64));
    m3v = fminf(m3v, __shfl_xor(m3v, 32, 64));
    if (lane < 4 && c0 + lane < nct) {
        float mv = (lane == 0) ? m0v : (lane == 1) ? m1v : (lane == 2) ? m2v : m3v;
        atomicMin((unsigned*)&cand_val[c0 + lane], __float_as_uint(mv));
    }
}

// ---------------- winners' exact dist rows, dot-form, 32-lane row groups ----------------
__global__ __launch_bounds__(256, 2)
void k_dists4(const float* __restrict__ fv, const float* __restrict__ mb,
              const float* __restrict__ fnorm, const float* __restrict__ mnorm,
              const int* __restrict__ ncand, const int* __restrict__ cand_pix,
              const int* __restrict__ cand_batch, const float* __restrict__ cand_val,
              float* __restrict__ exact_d) {
    int bg = blockIdx.y * 4;                 // batch group: 0..3 or 4..7
    int t = threadIdx.x, wid = t >> 6, lane = t & 63;
    int half = lane >> 5, j = lane & 31;
    int n = ncand[0]; if (n > 64) n = 64;

    int sp0, sp1, sp2, sp3;
#define WINNER(Q, OUTV) do { float v = -INF_F; int pix = 0x7fffffff; \
    if (lane < n && cand_batch[lane] == bg + (Q)) { v = cand_val[lane]; pix = cand_pix[lane]; } \
    _Pragma("unroll") \
    for (int s = 1; s < 64; s <<= 1) { \
        float ov = __shfl_xor(v, s, 64); int oi = __shfl_xor(pix, s, 64); \
        if (ov > v || (ov == v && oi < pix)) { v = ov; pix = oi; } } \
    OUTV = (pix == 0x7fffffff) ? (bg + (Q)) * 1024 : pix; } while (0)
    WINNER(0, sp0); WINNER(1, sp1); WINNER(2, sp2); WINNER(3, sp3);
#undef WINNER

    const float4* s0 = (const float4*)(fv + (size_t)sp0 * 512 + 16 * j);
    const float4* s1 = (const float4*)(fv + (size_t)sp1 * 512 + 16 * j);
    const float4* s2 = (const float4*)(fv + (size_t)sp2 * 512 + 16 * j);
    const float4* s3 = (const float4*)(fv + (size_t)sp3 * 512 + 16 * j);
    float4 a0 = s0[0], a1 = s0[1], a2 = s0[2], a3 = s0[3];
    float4 b0 = s1[0], b1 = s1[1], b2 = s1[2], b3 = s1[3];
    float4 g0 = s2[0], g1 = s2[1], g2 = s2[2], g3 = s2[3];
    float4 h0 = s3[0], h1 = s3[1], h2 = s3[2], h3 = s3[3];
    float fn0 = fnorm[sp0], fn1 = fnorm[sp1], fn2 = fnorm[sp2], fn3 = fnorm[sp3];

    int rbase = blockIdx.x * 64 + wid * 16;
    #pragma unroll 2
    for (int i = 0; i < 8; ++i) {
        int r = rbase + i * 2 + half;
        int rc = r < 24999 ? r : 24999;
        const float4* mp = (const float4*)(mb + (size_t)rc * 512 + 16 * j);
        float4 x0 = mp[0], x1 = mp[1], x2 = mp[2], x3 = mp[3];
        float q0 = dot4(x0,a0) + dot4(x1,a1) + dot4(x2,a2) + dot4(x3,a3);
        float q1 = dot4(x0,b0) + dot4(x1,b1) + dot4(x2,b2) + dot4(x3,b3);
        float q2 = dot4(x0,g0) + dot4(x1,g1) + dot4(x2,g2) + dot4(x3,g3);
        float q3 = dot4(x0,h0) + dot4(x1,h1) + dot4(x2,h2) + dot4(x3,h3);
        #pragma unroll
        for (int s = 1; s < 32; s <<= 1) {
            q0 += __shfl_xor(q0, s, 64);
            q1 += __shfl_xor(q1, s, 64);
            q2 += __shfl_xor(q2, s, 64);
            q3 += __shfl_xor(q3, s, 64);
        }
        if (j == 0 && r < 25000) {
            float mnr = mnorm[rc];
            exact_d[(size_t)(bg + 0) * 25000 + r] = fn0 + mnr - 2.0f * q0;
            exact_d[(size_t)(bg + 1) * 25000 + r] = fn1 + mnr - 2.0f * q1;
            exact_d[(size_t)(bg + 2) * 25000 + r] = fn2 + mnr - 2.0f * q2;
            exact_d[(size_t)(bg + 3) * 25000 + r] = fn3 + mnr - 2.0f * q3;
        }
    }
}

// ---------------- single-pass top-b (ascending dist, jax tie order) + softmax ----------------
__global__ __launch_bounds__(1024)
void k_final(const float* __restrict__ exact_d, const int* __restrict__ bptr,
             float* __restrict__ out_img) {
    __shared__ float wbv[16]; __shared__ int wbi[16];
    __shared__ float seld[128];
    __shared__ float gbv_s; __shared__ int gbi_s;
    int b = blockIdx.x, t = threadIdx.x, wid = t >> 6, lane = t & 63;
    int bval = bptr[0]; if (bval > 128) bval = 128; if (bval < 1) bval = 1;
    const float* dv = exact_d + (size_t)b * 25000;

    if (bval <= 16) {
        float tv[16]; int ti[16];
        #pragma unroll
        for (int k = 0; k < 16; ++k) { tv[k] = INF_F; ti[k] = 0x7fffffff; }
        for (int r = t; r < 25000; r += 1024) {
            float cv = dv[r]; int ci = r;
            if (cv < tv[15] || (cv == tv[15] && ci < ti[15])) {   // skip-guard
                #pragma unroll
                for (int k = 0; k < 16; ++k) {
                    bool better = (cv < tv[k]) || (cv == tv[k] && ci < ti[k]);
                    if (better) {
                        float t1 = tv[k]; tv[k] = cv; cv = t1;
                        int   t2 = ti[k]; ti[k] = ci; ci = t2;
                    }
                }
            }
        }
        for (int k = 0; k < bval; ++k) {
            float bv = tv[0]; int bi = ti[0];
            #pragma unroll
            for (int s = 1; s < 64; s <<= 1) {
                float ov = __shfl_xor(bv, s, 64); int oi = __shfl_xor(bi, s, 64);
                if (ov < bv || (ov == bv && oi < bi)) { bv = ov; bi = oi; }
            }
            if (lane == 0) { wbv[wid] = bv; wbi[wid] = bi; }
            __syncthreads();
            if (t == 0) {
                float fb = wbv[0]; int fi = wbi[0];
                for (int w2 = 1; w2 < 16; ++w2)
                    if (wbv[w2] < fb || (wbv[w2] == fb && wbi[w2] < fi)) { fb = wbv[w2]; fi = wbi[w2]; }
                seld[k] = sqrtf(fmaxf(fb, 0.0f));
                gbv_s = fb; gbi_s = fi;
            }
            __syncthreads();
            if (tv[0] == gbv_s && ti[0] == gbi_s) {       // unique index -> exactly one thread
                #pragma unroll
                for (int k2 = 0; k2 < 15; ++k2) { tv[k2] = tv[k2 + 1]; ti[k2] = ti[k2 + 1]; }
                tv[15] = INF_F; ti[15] = 0x7fffffff;
            }
        }
    } else {
        float lastV = -INF_F; int lastI = -1;
        for (int k = 0; k < bval; ++k) {
            float bv = INF_F; int bi = 0x7fffffff;
            for (int r = t; r < 25000; r += 1024) {
                float vv = dv[r];
                bool after = (vv > lastV) || (vv == lastV && r > lastI);
                if (after && (vv < bv || (vv == bv && r < bi))) { bv = vv; bi = r; }
            }
            #pragma unroll
            for (int s = 1; s < 64; s <<= 1) {
                float ov = __shfl_xor(bv, s, 64); int oi = __shfl_xor(bi, s, 64);
                if (ov < bv || (ov == bv && oi < bi)) { bv = ov; bi = oi; }
            }
            if (lane == 0) { wbv[wid] = bv; wbi[wid] = bi; }
            __syncthreads();
            if (t == 0) {
                float fb = wbv[0]; int fi = wbi[0];
                for (int w2 = 1; w2 < 16; ++w2)
                    if (wbv[w2] < fb || (wbv[w2] == fb && wbi[w2] < fi)) { fb = wbv[w2]; fi = wbi[w2]; }
                seld[k] = sqrtf(fmaxf(fb, 0.0f));
                gbv_s = fb; gbi_s = fi;
            }
            __syncthreads();
            lastV = gbv_s; lastI = gbi_s;
        }
    }

    if (t == 0) {
        float d0 = seld[0];
        float img = d0;
        if (bval > 1) {
            float m = -INF_F;
            for (int k = 0; k < bval; ++k) m = fmaxf(m, seld[k]);
            float s = 0.f;
            for (int k = 0; k < bval; ++k) s += expf(seld[k] - m);
            float p0 = expf(seld[0] - m) / s;
            img = d0 * (1.0f - p0);
        }
        out_img[b] = img;
    }
}

extern "C" void kernel_launch(void* const* d_in, const int* in_sizes, int n_in,
                              void* d_out, int out_size, void* d_ws, size_t ws_size,
                              hipStream_t stream) {
    const float* fv = (const float*)d_in[0];   // 8192 x 512
    const float* mb = (const float*)d_in[1];   // 25000 x 512
    const int*   bp = (const int*)d_in[2];     // scalar b
    float* out = (float*)d_out;                // [0..8191]=pixel_scores, [8192..8199]=image_scores

    char* w = (char*)d_ws;                     // ~35 MB total (proven footprint)
    unsigned short* fvb = (unsigned short*)w;                       // 8,388,608 B
    unsigned short* mbb = (unsigned short*)(w + 8388608);           // 25,600,000 B
    size_t o = 8388608 + 25600000;
    float* fnorm    = (float*)(w + o); o += 32768;
    float* mnorm    = (float*)(w + o); o += 100352;
    float* ps_sq    = (float*)(w + o); o += 32768;
    int*   ncand    = (int*)(w + o);   o += 256;
    int*   cand_pix = (int*)(w + o);   o += 256;
    int*   cand_bat = (int*)(w + o);   o += 256;
    float* cand_val = (float*)(w + o); o += 256;
    int*   sel_unused = (int*)(w + o); o += 256;
    float* exact_d  = (float*)(w + o); o += 800000;    // 8 x 25000 fp32
    (void)sel_unused;

    k_conv<<<8298, 256, 0, stream>>>(fv, mb, fvb, mbb, fnorm, mnorm, ps_sq, ncand, cand_val);
    k_gemm_min<<<12544, 256, 0, stream>>>(fvb, mbb, fnorm, mnorm, ps_sq);
    k_cand<<<8, 256, 0, stream>>>(ps_sq, out, ncand, cand_pix, cand_bat);
    k_score<<<dim3(391, 16), 256, 0, stream>>>(fv, mb, fnorm, mnorm, ncand, cand_pix, cand_val);
    k_dists4<<<dim3(391, 2), 256, 0, stream>>>(fv, mb, fnorm, mnorm, ncand, cand_pix, cand_bat, cand_val, exact_d);
    k_final<<<8, 1024, 0, stream>>>(exact_d, bp, out + 8192);
}